// Round 1
// baseline (2690.250 us; speedup 1.0000x reference)
//
#include <hip/hip_runtime.h>
#include <hip/hip_bf16.h>
#include <stdint.h>

#define NN 200000
#define EE 200000

// ---------- helpers ----------
__device__ __forceinline__ short f2bf(float f) {
  union { float f; unsigned u; } a; a.f = f;
  unsigned r = a.u + 0x7fffu + ((a.u >> 16) & 1u);   // round-to-nearest-even
  return (short)(r >> 16);
}
__device__ __forceinline__ float bf2f(unsigned short s) {
  union { float f; unsigned u; } a; a.u = ((unsigned)s) << 16;
  return a.f;
}
__device__ __forceinline__ float sigm(float x) { return 1.f / (1.f + __expf(-x)); }
__device__ __forceinline__ float tanh_fast(float x) {
  x = fminf(fmaxf(x, -15.f), 15.f);
  float e = __expf(2.f * x);
  return (e - 1.f) / (e + 1.f);
}

using bf16x8 = __attribute__((ext_vector_type(8))) short;
using f32x4  = __attribute__((ext_vector_type(4))) float;

__device__ __forceinline__ void load_lds16(const void* g, void* l) {
  __builtin_amdgcn_global_load_lds((const __attribute__((address_space(1))) void*)g,
                                   (__attribute__((address_space(3))) void*)l, 16, 0, 0);
}

// ---------- kernel 1: edge scatter-add into h_sum/c_sum (stored in d_out halves) ----------
__global__ void scatter_kernel(const float* __restrict__ h, const float* __restrict__ c,
                               const int* __restrict__ src, const int* __restrict__ dst,
                               float* __restrict__ hsum, float* __restrict__ csum) {
  int idx = blockIdx.x * 256 + threadIdx.x;            // EE*64 threads, 4 floats each
  if (idx >= EE * 64) return;
  int e = idx >> 6, q = idx & 63;
  int s = src[e], d = dst[e];
  const float4 hv = *(const float4*)(h + (size_t)s * 256 + q * 4);
  const float4 cv = *(const float4*)(c + (size_t)s * 256 + q * 4);
  float* hp = hsum + (size_t)d * 256 + q * 4;
  float* cp = csum + (size_t)d * 256 + q * 4;
  atomicAdd(hp + 0, hv.x); atomicAdd(hp + 1, hv.y);
  atomicAdd(hp + 2, hv.z); atomicAdd(hp + 3, hv.w);
  atomicAdd(cp + 0, cv.x); atomicAdd(cp + 1, cv.y);
  atomicAdd(cp + 2, cv.z); atomicAdd(cp + 3, cv.w);
}

// ---------- kernel 2: pack A = [x | h_sum] as bf16 [N,512] ----------
__global__ void pack_a_kernel(const float* __restrict__ x, const float* __restrict__ hsum,
                              short* __restrict__ A) {
  int idx = blockIdx.x * 256 + threadIdx.x;            // NN*64 threads, 8 elems each
  if (idx >= NN * 64) return;
  int n = idx >> 6, q = idx & 63;
  const float* s = (q < 32) ? (x    + (size_t)n * 256 + q * 8)
                            : (hsum + (size_t)n * 256 + (q - 32) * 8);
  float4 v0 = ((const float4*)s)[0];
  float4 v1 = ((const float4*)s)[1];
  int4 o;
  o.x = (int)(((unsigned)(unsigned short)f2bf(v0.x)) | ((unsigned)(unsigned short)f2bf(v0.y) << 16));
  o.y = (int)(((unsigned)(unsigned short)f2bf(v0.z)) | ((unsigned)(unsigned short)f2bf(v0.w) << 16));
  o.z = (int)(((unsigned)(unsigned short)f2bf(v1.x)) | ((unsigned)(unsigned short)f2bf(v1.y) << 16));
  o.w = (int)(((unsigned)(unsigned short)f2bf(v1.z)) | ((unsigned)(unsigned short)f2bf(v1.w) << 16));
  *(int4*)(A + (size_t)n * 512 + q * 8) = o;
}

// ---------- kernel 3: pack B^T [1024,512] bf16, columns interleaved p=4j+{i,o,u,f}; bias[1024] ----------
__global__ void pack_b_kernel(const float* __restrict__ W_iou, const float* __restrict__ U_iou,
                              const float* __restrict__ b_iou, const float* __restrict__ U_f_w,
                              const float* __restrict__ U_f_b,
                              short* __restrict__ Bp, float* __restrict__ biasp) {
  int idx = blockIdx.x * 256 + threadIdx.x;            // 1024*512
  if (idx >= 1024 * 512) return;
  int p = idx >> 9, k = idx & 511;
  int j = p >> 2, comp = p & 3;
  float v;
  if (comp < 3) v = (k < 256) ? W_iou[(size_t)(comp * 256 + j) * 256 + k]
                              : U_iou[(size_t)(comp * 256 + j) * 256 + (k - 256)];
  else          v = (k < 256) ? 0.f : U_f_w[(size_t)j * 256 + (k - 256)];
  Bp[(size_t)p * 512 + k] = f2bf(v);
  if (k == 0) biasp[p] = (comp < 3) ? b_iou[comp * 256 + j] : U_f_b[j];
}

// ---------- kernel 4: fused GEMM [N,512]x[512,1024]^T + gate epilogue ----------
__global__ __launch_bounds__(256)
void gemm_fused(const short* __restrict__ A, const short* __restrict__ Bp,
                const float* __restrict__ biasp,
                float* __restrict__ outh, float* __restrict__ outc) {
  __shared__ short smem[16384];                        // 32 KB: sA[128][64] + sB[128][64]; reused as Y[128][128]
  short* sA = smem;
  short* sB = smem + 8192;

  const int tid  = threadIdx.x;
  const int lane = tid & 63;
  const int wave = tid >> 6;
  const int wm = wave >> 1, wn = wave & 1;             // 2x2 waves, each 64x64
  const int row16 = lane & 15, quad = lane >> 4;

  const int mbase = blockIdx.y * 128;
  const int nbase = blockIdx.x * 128;
  const int wbase = wave * 64;

  f32x4 acc[4][4];
#pragma unroll
  for (int i = 0; i < 4; ++i)
#pragma unroll
    for (int j = 0; j < 4; ++j)
      acc[i][j] = (f32x4){0.f, 0.f, 0.f, 0.f};

  for (int kt = 0; kt < 512; kt += 64) {
#pragma unroll
    for (int i = 0; i < 4; ++i) {
      int s = i * 256 + tid;                           // 0..1023 : 16B segment id
      int r = s >> 3, seg = s & 7;
      int ra = mbase + r; if (ra > NN - 1) ra = NN - 1;
      const short* gA = A  + (size_t)ra * 512 + kt + seg * 8;
      const short* gB = Bp + (size_t)(nbase + r) * 512 + kt + seg * 8;
      load_lds16(gA, sA + (i * 256 + wbase) * 8);      // wave-uniform LDS base + lane*16
      load_lds16(gB, sB + (i * 256 + wbase) * 8);
    }
    __syncthreads();
#pragma unroll
    for (int kk = 0; kk < 64; kk += 32) {
      bf16x8 af[4], bfr[4];
#pragma unroll
      for (int mi = 0; mi < 4; ++mi)
        af[mi] = *(const bf16x8*)(sA + (wm * 64 + mi * 16 + row16) * 64 + kk + quad * 8);
#pragma unroll
      for (int ni = 0; ni < 4; ++ni)
        bfr[ni] = *(const bf16x8*)(sB + (wn * 64 + ni * 16 + row16) * 64 + kk + quad * 8);
#pragma unroll
      for (int mi = 0; mi < 4; ++mi)
#pragma unroll
        for (int ni = 0; ni < 4; ++ni)
          acc[mi][ni] = __builtin_amdgcn_mfma_f32_16x16x32_bf16(af[mi], bfr[ni], acc[mi][ni], 0, 0, 0);
    }
    __syncthreads();
  }

  // ---- epilogue: bias, bf16 LDS round-trip to regroup (i,o,u,f), gates ----
  float biasv[4];
#pragma unroll
  for (int ni = 0; ni < 4; ++ni)
    biasv[ni] = biasp[nbase + wn * 64 + ni * 16 + row16];

  short* Y = smem;                                     // [128][128] bf16
#pragma unroll
  for (int mi = 0; mi < 4; ++mi)
#pragma unroll
    for (int ni = 0; ni < 4; ++ni)
#pragma unroll
      for (int r = 0; r < 4; ++r) {
        int lrow = wm * 64 + mi * 16 + quad * 4 + r;   // C/D: row=(lane>>4)*4+reg, col=lane&15
        int lcol = wn * 64 + ni * 16 + row16;
        Y[lrow * 128 + lcol] = f2bf(acc[mi][ni][r] + biasv[ni]);
      }
  __syncthreads();

  const int jbase = nbase >> 2;                        // 32 gate-columns per block
#pragma unroll
  for (int t = 0; t < 16; ++t) {
    int u2 = t * 256 + tid;                            // 0..4095 = 128 rows x 32 j
    int row = u2 >> 5, jj = u2 & 31;
    int grow = mbase + row;
    if (grow < NN) {
      const unsigned short* yp = (const unsigned short*)Y + row * 128 + jj * 4;
      ushort4 y4 = *(const ushort4*)yp;                // (i,o,u,f) for one j
      float iv = bf2f(y4.x), ov = bf2f(y4.y), uv = bf2f(y4.z), fv = bf2f(y4.w);
      size_t off = (size_t)grow * 256 + (jbase + jj);
      float csum = outc[off];                          // c_sum lives here; same thread overwrites
      float cnew = sigm(iv) * tanh_fast(uv) + sigm(fv) * csum;
      float hnew = sigm(ov) * tanh_fast(cnew);
      outh[off] = hnew;
      outc[off] = cnew;
    }
  }
}

// ---------- launch ----------
extern "C" void kernel_launch(void* const* d_in, const int* in_sizes, int n_in,
                              void* d_out, int out_size, void* d_ws, size_t ws_size,
                              hipStream_t stream) {
  const float* x     = (const float*)d_in[0];
  const float* h     = (const float*)d_in[1];
  const float* c     = (const float*)d_in[2];
  const int*   src   = (const int*)d_in[3];
  const int*   dst   = (const int*)d_in[4];
  const float* W_iou = (const float*)d_in[5];
  const float* U_iou = (const float*)d_in[6];
  const float* b_iou = (const float*)d_in[7];
  const float* U_f_w = (const float*)d_in[8];
  const float* U_f_b = (const float*)d_in[9];

  float* outh = (float*)d_out;                 // h_new; holds h_sum until GEMM
  float* outc = outh + (size_t)NN * 256;       // c_new; holds c_sum until epilogue overwrite

  short* A     = (short*)d_ws;                 // [N,512] bf16 = 204.8 MB
  short* Bp    = A + (size_t)NN * 512;         // [1024,512] bf16 = 1 MB
  float* biasp = (float*)(Bp + 1024 * 512);    // [1024] f32

  hipMemsetAsync(d_out, 0, (size_t)out_size * sizeof(float), stream);

  scatter_kernel<<<(EE * 64) / 256, 256, 0, stream>>>(h, c, src, dst, outh, outc);
  pack_a_kernel<<<(NN * 64) / 256, 256, 0, stream>>>(x, outh, A);
  pack_b_kernel<<<(1024 * 512) / 256, 256, 0, stream>>>(W_iou, U_iou, b_iou, U_f_w, U_f_b, Bp, biasp);
  gemm_fused<<<dim3(8, 1563), 256, 0, stream>>>(A, Bp, biasp, outh, outc);
}